// Round 4
// baseline (91.809 us; speedup 1.0000x reference)
//
#include <hip/hip_runtime.h>
#include <hip/hip_fp16.h>
#include <math.h>

// Problem constants (from reference)
#define NUM_TREES 256
#define DEPTH 6
#define TREE_DIM 2
#define INPUT_DIM 256
#define BATCH 2048
#define NLEAF 64                     // 2^DEPTH
#define NCOLS (NUM_TREES * DEPTH)    // 1536
#define KDIM INPUT_DIM

typedef _Float16 half8 __attribute__((ext_vector_type(8)));
typedef float floatx4 __attribute__((ext_vector_type(4)));

// ---------------------------------------------------------------------------
// Kernel A: (1) convert inputs fp32 -> fp16 (independent prologue, hides the
// shuffle-chain latency of part 2), (2) sparsemax along axis 0 via bisection.
// One wave per (tree,depth) column; 16 halvings (tau to 2^-16 = 1.5e-5, far
// below the fp16 GEMM noise floor). selT output is fp16 COLUMN-major
// (k contiguous) = exactly the MFMA B-fragment order for kernel B.
// ---------------------------------------------------------------------------
__global__ __launch_bounds__(256) void sparsemax_bisect(
    const float* __restrict__ fsl,     // [256][1536] fp32
    const float* __restrict__ inputs,  // [2048][256] fp32
    _Float16* __restrict__ selT,       // [2048][256] fp16, col-major (pad 8/tree)
    _Float16* __restrict__ inH)        // [2048][256] fp16
{
    const int tid = threadIdx.x;
    // --- Part 1: fp32 -> fp16 conversion of inputs (65536 half8 jobs) ---
    {
        const int gid = blockIdx.x * 256 + tid;
        if (gid < (BATCH * INPUT_DIM) / 8) {
            const float4 v0 = ((const float4*)inputs)[gid * 2];
            const float4 v1 = ((const float4*)inputs)[gid * 2 + 1];
            half8 h;
            h[0] = (_Float16)v0.x; h[1] = (_Float16)v0.y;
            h[2] = (_Float16)v0.z; h[3] = (_Float16)v0.w;
            h[4] = (_Float16)v1.x; h[5] = (_Float16)v1.y;
            h[6] = (_Float16)v1.z; h[7] = (_Float16)v1.w;
            *(half8*)(inH + gid * 8) = h;
        }
    }

    // --- Part 2: sparsemax by bisection, one wave per column ---
    const int lane = tid & 63;
    const int wave = tid >> 6;                   // 0..3
    const int col  = blockIdx.x * 4 + wave;      // 0..1535
    const int n = col / 6;
    const int d = col - n * 6;

    float x[4];
#pragma unroll
    for (int j = 0; j < 4; ++j)
        x[j] = fsl[(j * 64 + lane) * NCOLS + col];

    float mx = fmaxf(fmaxf(x[0], x[1]), fmaxf(x[2], x[3]));
#pragma unroll
    for (int off = 32; off > 0; off >>= 1)
        mx = fmaxf(mx, __shfl_xor(mx, off));

    float lo = mx - 1.0f, hi = mx;
    for (int it = 0; it < 16; ++it) {
        const float mid = 0.5f * (lo + hi);
        float s = fmaxf(x[0] - mid, 0.0f) + fmaxf(x[1] - mid, 0.0f)
                + fmaxf(x[2] - mid, 0.0f) + fmaxf(x[3] - mid, 0.0f);
#pragma unroll
        for (int off = 32; off > 0; off >>= 1)
            s += __shfl_xor(s, off);
        if (s > 1.0f) lo = mid; else hi = mid;   // uniform across wave
    }
    const float tau = 0.5f * (lo + hi);

    _Float16* dst = selT + (n * 8 + d) * KDIM;
#pragma unroll
    for (int j = 0; j < 4; ++j)
        dst[j * 64 + lane] = (_Float16)fmaxf(x[j] - tau, 0.0f);
}

// ---------------------------------------------------------------------------
// Kernel B: fp16 MFMA GEMM (fv = inputs @ selectors) fused with sparsemoid ->
// leaf-weight DP -> response contraction.
// Block: 256 threads = 4 waves (2x2), tile M=128 x N=64 (8 trees), BK=64
// (4 K-steps, 8 barriers). A/B LDS rows padded to 72 halfs (144 B): fragment
// ds_read_b128 spreads 8 lanes over each of 8 bank-groups (even = optimal).
// fv C-tile LDS is UNIONed over the A/B tiles (used only after the K-loop):
// 38.9 KB total -> 4 blocks/CU capacity, grid 512 = 2 resident/CU.
// ---------------------------------------------------------------------------
#define BM 128
#define BN 64
#define BK 64
#define AP 72    // padded halfs per A row
#define BP 72    // padded halfs per B col
#define FVS 68   // fv stride: 68 % 32 == 4 -> 2-way (free) on C-writes

__global__ __launch_bounds__(256) void odt_mfma_kernel(
    const _Float16* __restrict__ inH,   // [2048][256] fp16
    const _Float16* __restrict__ selT,  // [2048][256] fp16 col-major
    const float* __restrict__ thr,      // [256][6]
    const float* __restrict__ logt,     // [256][6]
    const float* __restrict__ resp,     // [256][2][64]
    float* __restrict__ out)            // [2048][512]
{
    __shared__ union {
        struct {
            _Float16 A[BM][AP];   // 18 KB
            _Float16 B[BN][BP];   // 9 KB
        } s;
        float fv[BM][FVS];        // 34.8 KB
    } u;
    __shared__ float respS[8 * TREE_DIM * NLEAF]; // 4 KB

    const int tid = threadIdx.x;
    const int b0 = blockIdx.x * BM;
    const int treeBase = blockIdx.y * 8;
    const int colBase  = blockIdx.y * BN;

    // Stage response tile (8 trees x 128 floats = 256 float4).
    ((float4*)respS)[tid] = ((const float4*)(resp + treeBase * TREE_DIM * NLEAF))[tid];

    const int lane = tid & 63;
    const int w    = tid >> 6;
    const int wm   = w >> 1, wn = w & 1;
    const int l16  = lane & 15, quad = lane >> 4;

    floatx4 acc[4][2];
#pragma unroll
    for (int mt = 0; mt < 4; ++mt)
#pragma unroll
        for (int nt = 0; nt < 2; ++nt)
            acc[mt][nt] = (floatx4){0.f, 0.f, 0.f, 0.f};

    // Staging roles (fixed across K-steps)
    const int arow = tid >> 1, ahr = tid & 1;   // A: 128 rows x 2 half-rows (32 halfs)
    const int bcol = tid >> 2, bq  = tid & 3;   // B: 64 cols x 4 quarters (16 halfs)

    for (int k0 = 0; k0 < KDIM; k0 += BK) {
        __syncthreads();
        {
            const _Float16* ag = inH + (b0 + arow) * KDIM + k0 + ahr * 32;
            const half8 a0 = *(const half8*)(ag);
            const half8 a1 = *(const half8*)(ag + 8);
            const half8 a2 = *(const half8*)(ag + 16);
            const half8 a3 = *(const half8*)(ag + 24);
            *(half8*)&u.s.A[arow][ahr * 32 + 0]  = a0;
            *(half8*)&u.s.A[arow][ahr * 32 + 8]  = a1;
            *(half8*)&u.s.A[arow][ahr * 32 + 16] = a2;
            *(half8*)&u.s.A[arow][ahr * 32 + 24] = a3;
        }
        {
            const _Float16* bg = selT + (colBase + bcol) * KDIM + k0 + bq * 16;
            const half8 b0v = *(const half8*)(bg);
            const half8 b1v = *(const half8*)(bg + 8);
            *(half8*)&u.s.B[bcol][bq * 16 + 0] = b0v;
            *(half8*)&u.s.B[bcol][bq * 16 + 8] = b1v;
        }
        __syncthreads();

#pragma unroll
        for (int h = 0; h < 2; ++h) {
            const half8 bf0 = *(const half8*)&u.s.B[wn * 32 + l16][quad * 8 + h * 32];
            const half8 bf1 = *(const half8*)&u.s.B[wn * 32 + 16 + l16][quad * 8 + h * 32];
#pragma unroll
            for (int mt = 0; mt < 4; ++mt) {
                const half8 af = *(const half8*)&u.s.A[wm * 64 + mt * 16 + l16][quad * 8 + h * 32];
                acc[mt][0] = __builtin_amdgcn_mfma_f32_16x16x32_f16(af, bf0, acc[mt][0], 0, 0, 0);
                acc[mt][1] = __builtin_amdgcn_mfma_f32_16x16x32_f16(af, bf1, acc[mt][1], 0, 0, 0);
            }
        }
    }

    __syncthreads();   // all A/B ds_reads retired before union overwrite

    // C/D layout (m89-verified): col = lane&15, row = quad*4 + reg.
#pragma unroll
    for (int mt = 0; mt < 4; ++mt)
#pragma unroll
        for (int nt = 0; nt < 2; ++nt)
#pragma unroll
            for (int r = 0; r < 4; ++r)
                u.fv[wm * 64 + mt * 16 + quad * 4 + r][wn * 32 + nt * 16 + l16] = acc[mt][nt][r];
    __syncthreads();

    // Epilogue: 1024 (row, tree) pairs, 4 per thread; tree index wave-uniform.
#pragma unroll
    for (int p = 0; p < 4; ++p) {
        const int idx = tid + 256 * p;
        const int row = idx & 127;
        const int tl  = idx >> 7;           // tree 0..7 in block (wave-uniform)
        const int n   = treeBase + tl;
        const float* f = &u.fv[row][tl * 8];

        float sd[DEPTH];
#pragma unroll
        for (int d = 0; d < DEPTH; ++d) {
            const float tlg = (f[d] - thr[n * DEPTH + d]) * __expf(-logt[n * DEPTH + d]);
            sd[d] = fminf(fmaxf(0.5f + 0.5f * tlg, 0.0f), 1.0f);
        }
        float wv[NLEAF];
        wv[0] = 1.0f;
#pragma unroll
        for (int d = 0; d < DEPTH; ++d) {
            const int sz = 1 << d;
#pragma unroll
            for (int c2 = 0; c2 < NLEAF / 2; ++c2) {
                if (c2 < sz) {
                    const float t = wv[c2];
                    wv[c2]      = t * sd[d];
                    wv[c2 + sz] = t * (1.0f - sd[d]);
                }
            }
        }
        const float* r0 = &respS[tl * TREE_DIM * NLEAF];
        float o0 = 0.0f, o1 = 0.0f;
#pragma unroll
        for (int c2 = 0; c2 < NLEAF; ++c2) {
            o0 = fmaf(wv[c2], r0[c2], o0);
            o1 = fmaf(wv[c2], r0[NLEAF + c2], o1);
        }
        float2 o = {o0, o1};
        *(float2*)(out + (b0 + row) * (NUM_TREES * TREE_DIM) + n * TREE_DIM) = o;
    }
}

// ---------------------------------------------------------------------------
extern "C" void kernel_launch(void* const* d_in, const int* in_sizes, int n_in,
                              void* d_out, int out_size, void* d_ws, size_t ws_size,
                              hipStream_t stream) {
    const float* inputs = (const float*)d_in[0];  // [2048][256]
    const float* fsl    = (const float*)d_in[1];  // [256][256][6]
    const float* thr    = (const float*)d_in[2];  // [256][6]
    const float* logt   = (const float*)d_in[3];  // [256][6]
    const float* resp   = (const float*)d_in[4];  // [256][2][64]
    float* out = (float*)d_out;                   // [2048][512]
    _Float16* selT = (_Float16*)d_ws;                          // 1 MB
    _Float16* inH  = (_Float16*)((char*)d_ws + (1 << 20));     // 1 MB

    hipLaunchKernelGGL(sparsemax_bisect, dim3(NCOLS / 4), dim3(256), 0, stream,
                       fsl, inputs, selT, inH);
    hipLaunchKernelGGL(odt_mfma_kernel, dim3(BATCH / BM, NUM_TREES / 8), dim3(256),
                       0, stream, inH, selT, thr, logt, resp, out);
}

// Round 5
// 90.377 us; speedup vs baseline: 1.0158x; 1.0158x over previous
//
#include <hip/hip_runtime.h>
#include <hip/hip_fp16.h>
#include <math.h>

// Problem constants (from reference)
#define NUM_TREES 256
#define DEPTH 6
#define TREE_DIM 2
#define INPUT_DIM 256
#define BATCH 2048
#define NLEAF 64                     // 2^DEPTH
#define NCOLS (NUM_TREES * DEPTH)    // 1536
#define KDIM INPUT_DIM

typedef _Float16 half8 __attribute__((ext_vector_type(8)));
typedef float floatx4 __attribute__((ext_vector_type(4)));

// ---------------------------------------------------------------------------
// Kernel A (unchanged from R4): fp32->fp16 convert of inputs + sparsemax by
// bisection (16 halvings), one wave per (tree,depth) column. selT is fp16
// column-major (k contiguous, 8 padded cols/tree) = MFMA B-fragment order.
// ---------------------------------------------------------------------------
__global__ __launch_bounds__(256) void sparsemax_bisect(
    const float* __restrict__ fsl,     // [256][1536] fp32
    const float* __restrict__ inputs,  // [2048][256] fp32
    _Float16* __restrict__ selT,       // [2048][256] fp16, col-major (pad 8/tree)
    _Float16* __restrict__ inH)        // [2048][256] fp16
{
    const int tid = threadIdx.x;
    // --- Part 1: fp32 -> fp16 conversion of inputs ---
    {
        const int gid = blockIdx.x * 256 + tid;
        if (gid < (BATCH * INPUT_DIM) / 8) {
            const float4 v0 = ((const float4*)inputs)[gid * 2];
            const float4 v1 = ((const float4*)inputs)[gid * 2 + 1];
            half8 h;
            h[0] = (_Float16)v0.x; h[1] = (_Float16)v0.y;
            h[2] = (_Float16)v0.z; h[3] = (_Float16)v0.w;
            h[4] = (_Float16)v1.x; h[5] = (_Float16)v1.y;
            h[6] = (_Float16)v1.z; h[7] = (_Float16)v1.w;
            *(half8*)(inH + gid * 8) = h;
        }
    }

    // --- Part 2: sparsemax by bisection, one wave per column ---
    const int lane = tid & 63;
    const int wave = tid >> 6;                   // 0..3
    const int col  = blockIdx.x * 4 + wave;      // 0..1535
    const int n = col / 6;
    const int d = col - n * 6;

    float x[4];
#pragma unroll
    for (int j = 0; j < 4; ++j)
        x[j] = fsl[(j * 64 + lane) * NCOLS + col];

    float mx = fmaxf(fmaxf(x[0], x[1]), fmaxf(x[2], x[3]));
#pragma unroll
    for (int off = 32; off > 0; off >>= 1)
        mx = fmaxf(mx, __shfl_xor(mx, off));

    float lo = mx - 1.0f, hi = mx;
    for (int it = 0; it < 16; ++it) {
        const float mid = 0.5f * (lo + hi);
        float s = fmaxf(x[0] - mid, 0.0f) + fmaxf(x[1] - mid, 0.0f)
                + fmaxf(x[2] - mid, 0.0f) + fmaxf(x[3] - mid, 0.0f);
#pragma unroll
        for (int off = 32; off > 0; off >>= 1)
            s += __shfl_xor(s, off);
        if (s > 1.0f) lo = mid; else hi = mid;   // uniform across wave
    }
    const float tau = 0.5f * (lo + hi);

    _Float16* dst = selT + (n * 8 + d) * KDIM;
#pragma unroll
    for (int j = 0; j < 4; ++j)
        dst[j * 64 + lane] = (_Float16)fmaxf(x[j] - tau, 0.0f);
}

// ---------------------------------------------------------------------------
// Kernel B: fp16 MFMA GEMM fused with sparsemoid -> leaf DP -> response.
// R5 change: tile 64x64 (was 128x64) -> 1024 blocks = 4/CU block-level
// oversubscription; LDS 22.5 KB (7/CU capacity); launch_bounds(256,4) caps
// 128 VGPR -> 16 waves/CU. Attacks the vmcnt(0)+barrier latency exposure
// that made R3/R4 neutral. Epilogue uses DP to depth 5 only (wv[32]); the
// depth-6 factor folds into the response contraction, halving registers.
// ---------------------------------------------------------------------------
#define BM 64
#define BN 64
#define BK 64
#define AP 72    // padded halfs per A row (144 B)
#define BP 72    // padded halfs per B col
#define FVS 68   // fv stride: C-writes 2-way (free); epilogue reads 8-way on
                 // 2 instrs/pair - negligible vs alignment loss of odd strides

__global__ __launch_bounds__(256, 4) void odt_mfma_kernel(
    const _Float16* __restrict__ inH,   // [2048][256] fp16
    const _Float16* __restrict__ selT,  // [2048][256] fp16 col-major
    const float* __restrict__ thr,      // [256][6]
    const float* __restrict__ logt,     // [256][6]
    const float* __restrict__ resp,     // [256][2][64]
    float* __restrict__ out)            // [2048][512]
{
    __shared__ union {
        struct {
            _Float16 A[BM][AP];   // 9 KB
            _Float16 B[BN][BP];   // 9 KB
        } s;
        float fv[BM][FVS];        // 17.4 KB
    } u;
    __shared__ float respS[8 * TREE_DIM * NLEAF]; // 4 KB

    const int tid = threadIdx.x;
    const int b0 = blockIdx.x * BM;
    const int treeBase = blockIdx.y * 8;
    const int colBase  = blockIdx.y * BN;

    // Stage response tile (8 trees x 128 floats = 256 float4).
    ((float4*)respS)[tid] = ((const float4*)(resp + treeBase * TREE_DIM * NLEAF))[tid];

    const int lane = tid & 63;
    const int w    = tid >> 6;
    const int wm   = w >> 1, wn = w & 1;        // 2x2 wave grid, 32x32 tiles
    const int l16  = lane & 15, quad = lane >> 4;

    floatx4 acc[2][2];
#pragma unroll
    for (int mt = 0; mt < 2; ++mt)
#pragma unroll
        for (int nt = 0; nt < 2; ++nt)
            acc[mt][nt] = (floatx4){0.f, 0.f, 0.f, 0.f};

    // Staging roles: 64 rows/cols x 4 segments of 16 halfs (32 B/thread each).
    const int srow = tid >> 2, sseg = tid & 3;

    for (int k0 = 0; k0 < KDIM; k0 += BK) {
        __syncthreads();
        {
            const _Float16* ag = inH + (b0 + srow) * KDIM + k0 + sseg * 16;
            const half8 a0 = *(const half8*)(ag);
            const half8 a1 = *(const half8*)(ag + 8);
            *(half8*)&u.s.A[srow][sseg * 16 + 0] = a0;
            *(half8*)&u.s.A[srow][sseg * 16 + 8] = a1;
            const _Float16* bg = selT + (colBase + srow) * KDIM + k0 + sseg * 16;
            const half8 bv0 = *(const half8*)(bg);
            const half8 bv1 = *(const half8*)(bg + 8);
            *(half8*)&u.s.B[srow][sseg * 16 + 0] = bv0;
            *(half8*)&u.s.B[srow][sseg * 16 + 8] = bv1;
        }
        __syncthreads();

#pragma unroll
        for (int h = 0; h < 2; ++h) {
            const half8 bf0 = *(const half8*)&u.s.B[wn * 32 + l16][quad * 8 + h * 32];
            const half8 bf1 = *(const half8*)&u.s.B[wn * 32 + 16 + l16][quad * 8 + h * 32];
            const half8 af0 = *(const half8*)&u.s.A[wm * 32 + l16][quad * 8 + h * 32];
            const half8 af1 = *(const half8*)&u.s.A[wm * 32 + 16 + l16][quad * 8 + h * 32];
            acc[0][0] = __builtin_amdgcn_mfma_f32_16x16x32_f16(af0, bf0, acc[0][0], 0, 0, 0);
            acc[0][1] = __builtin_amdgcn_mfma_f32_16x16x32_f16(af0, bf1, acc[0][1], 0, 0, 0);
            acc[1][0] = __builtin_amdgcn_mfma_f32_16x16x32_f16(af1, bf0, acc[1][0], 0, 0, 0);
            acc[1][1] = __builtin_amdgcn_mfma_f32_16x16x32_f16(af1, bf1, acc[1][1], 0, 0, 0);
        }
    }

    __syncthreads();   // all A/B ds_reads retired before union overwrite

    // C/D layout (m89-verified): col = lane&15, row = quad*4 + reg.
#pragma unroll
    for (int mt = 0; mt < 2; ++mt)
#pragma unroll
        for (int nt = 0; nt < 2; ++nt)
#pragma unroll
            for (int r = 0; r < 4; ++r)
                u.fv[wm * 32 + mt * 16 + quad * 4 + r][wn * 32 + nt * 16 + l16] = acc[mt][nt][r];
    __syncthreads();

    // Epilogue: 512 (row, tree) pairs, 2 per thread; tree index wave-uniform.
#pragma unroll
    for (int p = 0; p < 2; ++p) {
        const int idx = tid + 256 * p;
        const int row = idx & 63;
        const int tl  = idx >> 6;           // 0..7, wave-uniform
        const int n   = treeBase + tl;
        const float* f = &u.fv[row][tl * 8];

        float sd[DEPTH];
#pragma unroll
        for (int d = 0; d < DEPTH; ++d) {
            const float tlg = (f[d] - thr[n * DEPTH + d]) * __expf(-logt[n * DEPTH + d]);
            sd[d] = fminf(fmaxf(0.5f + 0.5f * tlg, 0.0f), 1.0f);
        }
        // DP over depths 0..4 only (32 leaves); depth-5 factor folds into
        // the contraction. Leaf bit d == 1 -> factor (1 - sd[d]).
        float wv[NLEAF / 2];
        wv[0] = 1.0f;
#pragma unroll
        for (int d = 0; d < 5; ++d) {
            const int sz = 1 << d;
#pragma unroll
            for (int c2 = 0; c2 < 16; ++c2) {
                if (c2 < sz) {
                    const float t = wv[c2];
                    wv[c2]      = t * sd[d];
                    wv[c2 + sz] = t * (1.0f - sd[d]);
                }
            }
        }
        const float* r0 = &respS[tl * TREE_DIM * NLEAF];
        float a0 = 0.f, b0s = 0.f, a1 = 0.f, b1s = 0.f;
#pragma unroll
        for (int c2 = 0; c2 < 32; ++c2) {
            a0  = fmaf(wv[c2], r0[c2], a0);
            b0s = fmaf(wv[c2], r0[c2 + 32], b0s);
            a1  = fmaf(wv[c2], r0[NLEAF + c2], a1);
            b1s = fmaf(wv[c2], r0[NLEAF + c2 + 32], b1s);
        }
        const float s5 = sd[5], s5b = 1.0f - sd[5];
        float2 o;
        o.x = s5 * a0 + s5b * b0s;
        o.y = s5 * a1 + s5b * b1s;
        *(float2*)(out + (b0 + row) * (NUM_TREES * TREE_DIM) + n * TREE_DIM) = o;
    }
}

// ---------------------------------------------------------------------------
extern "C" void kernel_launch(void* const* d_in, const int* in_sizes, int n_in,
                              void* d_out, int out_size, void* d_ws, size_t ws_size,
                              hipStream_t stream) {
    const float* inputs = (const float*)d_in[0];  // [2048][256]
    const float* fsl    = (const float*)d_in[1];  // [256][256][6]
    const float* thr    = (const float*)d_in[2];  // [256][6]
    const float* logt   = (const float*)d_in[3];  // [256][6]
    const float* resp   = (const float*)d_in[4];  // [256][2][64]
    float* out = (float*)d_out;                   // [2048][512]
    _Float16* selT = (_Float16*)d_ws;                          // 1 MB
    _Float16* inH  = (_Float16*)((char*)d_ws + (1 << 20));     // 1 MB

    hipLaunchKernelGGL(sparsemax_bisect, dim3(NCOLS / 4), dim3(256), 0, stream,
                       fsl, inputs, selT, inH);
    hipLaunchKernelGGL(odt_mfma_kernel, dim3(BATCH / BM, NUM_TREES / 8), dim3(256),
                       0, stream, inH, selT, thr, logt, resp, out);
}

// Round 6
// 89.877 us; speedup vs baseline: 1.0215x; 1.0056x over previous
//
#include <hip/hip_runtime.h>
#include <hip/hip_fp16.h>
#include <math.h>

// Problem constants (from reference)
#define NUM_TREES 256
#define DEPTH 6
#define TREE_DIM 2
#define INPUT_DIM 256
#define BATCH 2048
#define NLEAF 64                     // 2^DEPTH
#define NCOLS (NUM_TREES * DEPTH)    // 1536
#define KDIM INPUT_DIM

typedef _Float16 half8 __attribute__((ext_vector_type(8)));
typedef float floatx4 __attribute__((ext_vector_type(4)));

// ---------------------------------------------------------------------------
// Kernel A (unchanged): fp32->fp16 convert of inputs + sparsemax by bisection
// (16 halvings), one wave per (tree,depth) column. selT is fp16 column-major
// (k contiguous, 8 padded cols/tree) = MFMA B-fragment order.
// ---------------------------------------------------------------------------
__global__ __launch_bounds__(256) void sparsemax_bisect(
    const float* __restrict__ fsl,     // [256][1536] fp32
    const float* __restrict__ inputs,  // [2048][256] fp32
    _Float16* __restrict__ selT,       // [2048][256] fp16, col-major (pad 8/tree)
    _Float16* __restrict__ inH)        // [2048][256] fp16
{
    const int tid = threadIdx.x;
    {
        const int gid = blockIdx.x * 256 + tid;
        if (gid < (BATCH * INPUT_DIM) / 8) {
            const float4 v0 = ((const float4*)inputs)[gid * 2];
            const float4 v1 = ((const float4*)inputs)[gid * 2 + 1];
            half8 h;
            h[0] = (_Float16)v0.x; h[1] = (_Float16)v0.y;
            h[2] = (_Float16)v0.z; h[3] = (_Float16)v0.w;
            h[4] = (_Float16)v1.x; h[5] = (_Float16)v1.y;
            h[6] = (_Float16)v1.z; h[7] = (_Float16)v1.w;
            *(half8*)(inH + gid * 8) = h;
        }
    }

    const int lane = tid & 63;
    const int wave = tid >> 6;
    const int col  = blockIdx.x * 4 + wave;      // 0..1535
    const int n = col / 6;
    const int d = col - n * 6;

    float x[4];
#pragma unroll
    for (int j = 0; j < 4; ++j)
        x[j] = fsl[(j * 64 + lane) * NCOLS + col];

    float mx = fmaxf(fmaxf(x[0], x[1]), fmaxf(x[2], x[3]));
#pragma unroll
    for (int off = 32; off > 0; off >>= 1)
        mx = fmaxf(mx, __shfl_xor(mx, off));

    float lo = mx - 1.0f, hi = mx;
    for (int it = 0; it < 16; ++it) {
        const float mid = 0.5f * (lo + hi);
        float s = fmaxf(x[0] - mid, 0.0f) + fmaxf(x[1] - mid, 0.0f)
                + fmaxf(x[2] - mid, 0.0f) + fmaxf(x[3] - mid, 0.0f);
#pragma unroll
        for (int off = 32; off > 0; off >>= 1)
            s += __shfl_xor(s, off);
        if (s > 1.0f) lo = mid; else hi = mid;
    }
    const float tau = 0.5f * (lo + hi);

    _Float16* dst = selT + (n * 8 + d) * KDIM;
#pragma unroll
    for (int j = 0; j < 4; ++j)
        dst[j * 64 + lane] = (_Float16)fmaxf(x[j] - tau, 0.0f);
}

// ---------------------------------------------------------------------------
// Kernel B: fp16 MFMA GEMM fused with sparsemoid -> leaf DP -> response.
// R6 changes vs R5 (same 64x64x64 tiling, 1024 blocks):
//  1. Register prefetch double-buffer: K-step k+1's global loads issue right
//     after staging k to LDS, hiding L2/L3 latency under the MFMA phase
//     (removes the per-step vmcnt(0) drain exposure).
//  2. Out stores coalesced: results staged in outS LDS, written as float4
//     (16 lines/wave-store instead of 64 for the float2 scatter).
//  3. FVS 68 -> 67: epilogue fv reads drop 8-way -> 2-way bank aliasing.
// ---------------------------------------------------------------------------
#define BM 64
#define BN 64
#define BK 64
#define AP 72    // padded halfs per A row (144 B): even 8-group spread on b128
#define BP 72
#define FVS 67   // odd stride: C-writes <=2-way, epilogue b32 reads 2-way
#define OSP 36   // outS stride (floats): float4-aligned, even 8-group spread

__global__ __launch_bounds__(256, 4) void odt_mfma_kernel(
    const _Float16* __restrict__ inH,   // [2048][256] fp16
    const _Float16* __restrict__ selT,  // [2048][256] fp16 col-major
    const float* __restrict__ thr,      // [256][6]
    const float* __restrict__ logt,     // [256][6]
    const float* __restrict__ resp,     // [256][2][64]
    float* __restrict__ out)            // [2048][512]
{
    __shared__ union {
        struct {
            _Float16 A[BM][AP];   // 9 KB
            _Float16 B[BN][BP];   // 9 KB
        } s;
        float fv[BM][FVS];        // 16.75 KB
    } u;
    __shared__ float respS[8 * TREE_DIM * NLEAF]; // 4 KB
    __shared__ float outS[BM][OSP];               // 9 KB

    const int tid = threadIdx.x;
    const int b0 = blockIdx.x * BM;
    const int treeBase = blockIdx.y * 8;
    const int colBase  = blockIdx.y * BN;

    // Stage response tile (8 trees x 128 floats = 256 float4).
    ((float4*)respS)[tid] = ((const float4*)(resp + treeBase * TREE_DIM * NLEAF))[tid];

    const int lane = tid & 63;
    const int w    = tid >> 6;
    const int wm   = w >> 1, wn = w & 1;        // 2x2 wave grid, 32x32 tiles
    const int l16  = lane & 15, quad = lane >> 4;

    floatx4 acc[2][2];
#pragma unroll
    for (int mt = 0; mt < 2; ++mt)
#pragma unroll
        for (int nt = 0; nt < 2; ++nt)
            acc[mt][nt] = (floatx4){0.f, 0.f, 0.f, 0.f};

    // Staging roles: 64 rows/cols x 4 segments of 16 halfs (32 B/thread each).
    const int srow = tid >> 2, sseg = tid & 3;
    const _Float16* aBase = inH  + (b0 + srow) * KDIM + sseg * 16;
    const _Float16* bBase = selT + (colBase + srow) * KDIM + sseg * 16;

    // Prefetch K-step 0 into registers.
    half8 pa0 = *(const half8*)(aBase);
    half8 pa1 = *(const half8*)(aBase + 8);
    half8 pb0 = *(const half8*)(bBase);
    half8 pb1 = *(const half8*)(bBase + 8);

#pragma unroll
    for (int k0 = 0; k0 < KDIM; k0 += BK) {
        __syncthreads();
        // Stage prefetched registers into LDS.
        *(half8*)&u.s.A[srow][sseg * 16 + 0] = pa0;
        *(half8*)&u.s.A[srow][sseg * 16 + 8] = pa1;
        *(half8*)&u.s.B[srow][sseg * 16 + 0] = pb0;
        *(half8*)&u.s.B[srow][sseg * 16 + 8] = pb1;
        // Issue next K-step's loads now; latency hides under the MFMA phase.
        if (k0 + BK < KDIM) {
            pa0 = *(const half8*)(aBase + k0 + BK);
            pa1 = *(const half8*)(aBase + k0 + BK + 8);
            pb0 = *(const half8*)(bBase + k0 + BK);
            pb1 = *(const half8*)(bBase + k0 + BK + 8);
        }
        __syncthreads();

#pragma unroll
        for (int h = 0; h < 2; ++h) {
            const half8 bf0 = *(const half8*)&u.s.B[wn * 32 + l16][quad * 8 + h * 32];
            const half8 bf1 = *(const half8*)&u.s.B[wn * 32 + 16 + l16][quad * 8 + h * 32];
            const half8 af0 = *(const half8*)&u.s.A[wm * 32 + l16][quad * 8 + h * 32];
            const half8 af1 = *(const half8*)&u.s.A[wm * 32 + 16 + l16][quad * 8 + h * 32];
            acc[0][0] = __builtin_amdgcn_mfma_f32_16x16x32_f16(af0, bf0, acc[0][0], 0, 0, 0);
            acc[0][1] = __builtin_amdgcn_mfma_f32_16x16x32_f16(af0, bf1, acc[0][1], 0, 0, 0);
            acc[1][0] = __builtin_amdgcn_mfma_f32_16x16x32_f16(af1, bf0, acc[1][0], 0, 0, 0);
            acc[1][1] = __builtin_amdgcn_mfma_f32_16x16x32_f16(af1, bf1, acc[1][1], 0, 0, 0);
        }
    }

    __syncthreads();   // all A/B ds_reads retired before union overwrite

    // C/D layout (m89-verified): col = lane&15, row = quad*4 + reg.
#pragma unroll
    for (int mt = 0; mt < 2; ++mt)
#pragma unroll
        for (int nt = 0; nt < 2; ++nt)
#pragma unroll
            for (int r = 0; r < 4; ++r)
                u.fv[wm * 32 + mt * 16 + quad * 4 + r][wn * 32 + nt * 16 + l16] = acc[mt][nt][r];
    __syncthreads();

    // Epilogue: 512 (row, tree) pairs, 2 per thread; tree index wave-uniform.
#pragma unroll
    for (int p = 0; p < 2; ++p) {
        const int idx = tid + 256 * p;
        const int row = idx & 63;
        const int tl  = idx >> 6;           // 0..7, wave-uniform
        const int n   = treeBase + tl;
        const float* f = &u.fv[row][tl * 8];

        float sd[DEPTH];
#pragma unroll
        for (int d = 0; d < DEPTH; ++d) {
            const float tlg = (f[d] - thr[n * DEPTH + d]) * __expf(-logt[n * DEPTH + d]);
            sd[d] = fminf(fmaxf(0.5f + 0.5f * tlg, 0.0f), 1.0f);
        }
        // DP over depths 0..4 (32 leaves); depth-5 factor folds into the
        // contraction. Leaf bit d == 1 -> factor (1 - sd[d]).
        float wv[NLEAF / 2];
        wv[0] = 1.0f;
#pragma unroll
        for (int d = 0; d < 5; ++d) {
            const int sz = 1 << d;
#pragma unroll
            for (int c2 = 0; c2 < 16; ++c2) {
                if (c2 < sz) {
                    const float t = wv[c2];
                    wv[c2]      = t * sd[d];
                    wv[c2 + sz] = t * (1.0f - sd[d]);
                }
            }
        }
        const float* r0 = &respS[tl * TREE_DIM * NLEAF];
        float a0 = 0.f, c0 = 0.f, a1 = 0.f, c1 = 0.f;
#pragma unroll
        for (int c2 = 0; c2 < 32; ++c2) {
            a0 = fmaf(wv[c2], r0[c2], a0);
            c0 = fmaf(wv[c2], r0[c2 + 32], c0);
            a1 = fmaf(wv[c2], r0[NLEAF + c2], a1);
            c1 = fmaf(wv[c2], r0[NLEAF + c2 + 32], c1);
        }
        const float s5 = sd[5], s5b = 1.0f - sd[5];
        float2 o;
        o.x = s5 * a0 + s5b * c0;
        o.y = s5 * a1 + s5b * c1;
        *(float2*)&outS[row][tl * 2] = o;   // LDS stage (8-B aligned)
    }
    __syncthreads();

    // Coalesced out write: block footprint = 64 rows x 16 consecutive floats.
    // Thread t -> row t>>2, float4 segment t&3: 16 lines per wave-store.
    {
        const int wrow = tid >> 2, wc = tid & 3;
        const float4 v = *(const float4*)&outS[wrow][wc * 4];
        *(float4*)(out + (b0 + wrow) * (NUM_TREES * TREE_DIM) + treeBase * 2 + wc * 4) = v;
    }
}

// ---------------------------------------------------------------------------
extern "C" void kernel_launch(void* const* d_in, const int* in_sizes, int n_in,
                              void* d_out, int out_size, void* d_ws, size_t ws_size,
                              hipStream_t stream) {
    const float* inputs = (const float*)d_in[0];  // [2048][256]
    const float* fsl    = (const float*)d_in[1];  // [256][256][6]
    const float* thr    = (const float*)d_in[2];  // [256][6]
    const float* logt   = (const float*)d_in[3];  // [256][6]
    const float* resp   = (const float*)d_in[4];  // [256][2][64]
    float* out = (float*)d_out;                   // [2048][512]
    _Float16* selT = (_Float16*)d_ws;                          // 1 MB
    _Float16* inH  = (_Float16*)((char*)d_ws + (1 << 20));     // 1 MB

    hipLaunchKernelGGL(sparsemax_bisect, dim3(NCOLS / 4), dim3(256), 0, stream,
                       fsl, inputs, selT, inH);
    hipLaunchKernelGGL(odt_mfma_kernel, dim3(BATCH / BM, NUM_TREES / 8), dim3(256),
                       0, stream, inH, selT, thr, logt, resp, out);
}